// Round 14
// baseline (14154.266 us; speedup 1.0000x reference)
//
#include <hip/hip_runtime.h>

#define H 4096
#define IN 64
#define OUTD 64
#define SEQ 4096
#define NBLK 256
#define ROWS_PER_BLK 16
#define NTHR 1024
#define SENT 0x7F7F7F7Fu   // 3.39e38f; tanh output in [-1,1] can never equal it

// ---- device-coherent (L2-bypassing, MALL-point) accessors -----------------
__device__ __forceinline__ uint4 cpoll1(const unsigned* p) {
    uint4 v;
    asm volatile("global_load_dwordx4 %0, %1, off sc0 sc1\n\t"
                 "s_waitcnt vmcnt(0)"
                 : "=&v"(v) : "v"(p) : "memory");
    return v;
}
__device__ __forceinline__ void coherent_store_f32(float* p, float v) {
    asm volatile("global_store_dword %0, %1, off sc0 sc1"
                 :: "v"(p), "v"(v) : "memory");
}

__device__ __forceinline__ float row16_allreduce(float x) {
    x += __int_as_float(__builtin_amdgcn_update_dpp(0, __float_as_int(x), 0x128, 0xf, 0xf, false)); // row_ror:8
    x += __int_as_float(__builtin_amdgcn_update_dpp(0, __float_as_int(x), 0x124, 0xf, 0xf, false)); // row_ror:4
    x += __int_as_float(__builtin_amdgcn_update_dpp(0, __float_as_int(x), 0x122, 0xf, 0xf, false)); // row_ror:2
    x += __int_as_float(__builtin_amdgcn_update_dpp(0, __float_as_int(x), 0x121, 0xf, 0xf, false)); // row_ror:1
    return x;
}
__device__ __forceinline__ float quad4_allreduce(float x) {
    x += __int_as_float(__builtin_amdgcn_update_dpp(0, __float_as_int(x), 0xB1, 0xf, 0xf, false)); // perm 1,0,3,2
    x += __int_as_float(__builtin_amdgcn_update_dpp(0, __float_as_int(x), 0x4E, 0xf, 0xf, false)); // perm 2,3,0,1
    return x;
}
__device__ __forceinline__ float wave64_allreduce(float x) {
#pragma unroll
    for (int m = 1; m < 64; m <<= 1) x += __shfl_xor(x, m, 64);
    return x;
}

__global__ __launch_bounds__(NTHR, 4)
void esn_scan(const float* __restrict__ inputs,   // (SEQ, IN)
              const float* __restrict__ W_in,     // (H, IN)
              const float* __restrict__ W_res,    // (H, H)
              const float* __restrict__ W_out,    // (OUTD, 4161)
              float* __restrict__ out_states,     // (SEQ, H), sentinel-prefilled
              float* __restrict__ outputs)        // (SEQ, OUTD)
{
    __shared__ alignas(16) float4 s_state4[H / 4];        // 1024 swizzled quads
    __shared__ alignas(16) float4 s_copy[H / 4];          // parked turn state
    __shared__ alignas(16) float s_win[ROWS_PER_BLK][65]; // padded
    __shared__ alignas(16) float s_part[2][16][20];       // [parity][k(wave)][row+pad]
    __shared__ alignas(16) float s_u[IN];                 // wave0-local

    const int tid  = threadIdx.x;
    const int bid  = blockIdx.x;
    const int row0 = bid * ROWS_PER_BLK;
    const int wave = tid >> 6;
    const int lane = tid & 63;
    const int rg   = lane >> 4;   // 0..3
    const int cgi  = lane & 15;   // 0..15
    const int col0 = wave * 256 + cgi * 16;

    // staging: thread tid polls quad tid (cols 4*tid..4*tid+3)
    // LDS slot = 64*(qi>>6) + 16*(qi&3) + ((qi>>2)&15)
    const int sp    = tid >> 2;
    const int sq    = tid & 3;
    const int sslot = 64 * (sp >> 4) + 16 * sq + (sp & 15);
    const int scol  = sp * 16 + sq * 4;

    // readout dot for parked row s, output o (wave-wide; reads s_copy)
    auto out_dot = [&](int s, int o) {
        const float* wrow = W_out + (size_t)o * (1 + IN + H);
        float acc = 0.f;
#pragma unroll
        for (int j = 0; j < 16; ++j) {
            const int qi   = lane + 64 * j;
            const int slot = 64 * j + 16 * (lane & 3) + ((lane >> 2) & 15);
            float4 sv = s_copy[slot];
            float4 wq;   // wrow+65 only 4B-aligned -> memcpy (dword loads, L2-hot)
            __builtin_memcpy(&wq, wrow + 65 + 4 * qi, 16);
            acc = fmaf(wq.x, sv.x, acc);
            acc = fmaf(wq.y, sv.y, acc);
            acc = fmaf(wq.z, sv.z, acc);
            acc = fmaf(wq.w, sv.w, acc);
        }
        if (lane < 16) {
            float4 wi, iu;
            __builtin_memcpy(&wi, wrow + 1 + 4 * lane, 16);
            iu = *(const float4*)(inputs + (size_t)s * IN + 4 * lane);
            acc = fmaf(wi.x, iu.x, acc);
            acc = fmaf(wi.y, iu.y, acc);
            acc = fmaf(wi.z, iu.z, acc);
            acc = fmaf(wi.w, iu.w, acc);
            if (lane == 0) acc += wrow[0];   // bias
        }
        acc = wave64_allreduce(acc);
        if (lane == 0) outputs[(size_t)s * OUTD + o] = acc;
    };

    for (int idx = tid; idx < ROWS_PER_BLK * IN; idx += NTHR)
        s_win[idx >> 6][idx & 63] = W_in[(size_t)row0 * IN + idx];

    float w[4][16];
#pragma unroll
    for (int j = 0; j < 4; ++j) {
        const float* src = W_res + (size_t)(row0 + 4 * rg + j) * H + col0;
#pragma unroll
        for (int q = 0; q < 4; ++q) {
            float4 v = *(const float4*)(src + 4 * q);
            w[j][4 * q + 0] = v.x; w[j][4 * q + 1] = v.y;
            w[j][4 * q + 2] = v.z; w[j][4 * q + 3] = v.w;
        }
    }
    __syncthreads();   // s_win visible to wave0 before first phase-3

    for (int t = 0; t < SEQ; ++t) {
        const int par = t & 1;
        if (tid < 16)   // wave0-local; program-order safe vs phase-3 reads
            ((float4*)s_u)[tid] = ((const float4*)(inputs + (size_t)t * IN))[tid];

        // ---- stage state row t-1: one-hop 16B poll, calibrated backoff, no B1
        if (t == 0) {
            s_state4[sslot] = make_float4(0.f, 0.f, 0.f, 0.f);
        } else {
            const unsigned* p =
                (const unsigned*)(out_states + (size_t)(t - 1) * H + scol);
            uint4 v = cpoll1(p);
            if ((v.x == SENT) | (v.y == SENT) | (v.z == SENT) | (v.w == SENT)) {
                __builtin_amdgcn_s_sleep(8);   // skip publish dead-window
                for (;;) {
                    v = cpoll1(p);
                    if ((v.x != SENT) & (v.y != SENT) &
                        (v.z != SENT) & (v.w != SENT))
                        break;
                    __builtin_amdgcn_s_sleep(2);
                }
            }
            float4 f;
            f.x = __uint_as_float(v.x); f.y = __uint_as_float(v.y);
            f.z = __uint_as_float(v.z); f.w = __uint_as_float(v.w);
            s_state4[sslot] = f;
        }

        // ---- phase 2: 4 rows x 16 cols of FMA per lane, weights in VGPRs
        float a0 = 0.f, a1 = 0.f, a2 = 0.f, a3 = 0.f;
#pragma unroll
        for (int q = 0; q < 4; ++q) {
            float4 sv = s_state4[wave * 64 + q * 16 + cgi];
            a0 = fmaf(w[0][4*q+0], sv.x, a0); a0 = fmaf(w[0][4*q+1], sv.y, a0);
            a0 = fmaf(w[0][4*q+2], sv.z, a0); a0 = fmaf(w[0][4*q+3], sv.w, a0);
            a1 = fmaf(w[1][4*q+0], sv.x, a1); a1 = fmaf(w[1][4*q+1], sv.y, a1);
            a1 = fmaf(w[1][4*q+2], sv.z, a1); a1 = fmaf(w[1][4*q+3], sv.w, a1);
            a2 = fmaf(w[2][4*q+0], sv.x, a2); a2 = fmaf(w[2][4*q+1], sv.y, a2);
            a2 = fmaf(w[2][4*q+2], sv.z, a2); a2 = fmaf(w[2][4*q+3], sv.w, a2);
            a3 = fmaf(w[3][4*q+0], sv.x, a3); a3 = fmaf(w[3][4*q+1], sv.y, a3);
            a3 = fmaf(w[3][4*q+2], sv.z, a3); a3 = fmaf(w[3][4*q+3], sv.w, a3);
        }
        a0 = row16_allreduce(a0);
        a1 = row16_allreduce(a1);
        a2 = row16_allreduce(a2);
        a3 = row16_allreduce(a3);
        if (cgi == 0) {
            float4 pv; pv.x = a0; pv.y = a1; pv.z = a2; pv.w = a3;
            *(float4*)&s_part[par][wave][4 * rg] = pv;
        }
        __syncthreads();   // B2: the only barrier per step

        // ---- phase 3: wave0 finishes all 16 rows; ONE coalesced 64B publish.
        if (wave == 0) {
            const int row = lane >> 2;  // 0..15
            const int j   = lane & 3;   // partial group
            float v = s_part[par][4*j+0][row] + s_part[par][4*j+1][row]
                    + s_part[par][4*j+2][row] + s_part[par][4*j+3][row];
#pragma unroll
            for (int e = 0; e < 16; ++e)
                v = fmaf(s_win[row][16*j + e], s_u[16*j + e], v);
            v = quad4_allreduce(v);
            if (j == 0)
                coherent_store_f32(&out_states[(size_t)t * H + row0 + row],
                                   tanhf(v));
        } else if (wave >= 8 && t >= 1) {
            // ---- fused readout: one output per wave per step, k=1..8 after
            // this block's turn. Runs inside the post-B2 dead window (the next
            // poll can't hit for ~400ns anyway) -> off the critical path.
            const int k = (t - 1 - bid) & 255;
            if (k >= 1 && k <= 8) {
                const int s = t - 1 - k;
                if (s >= 0) out_dot(s, (wave - 8) + 8 * (k - 1));
            }
        }
        // ---- turn park: snapshot state row t-1 for readout (wave-local copy;
        // next-iter staging writes are also wave-local -> program-order safe).
        if (t >= 1 && (((t - 1 - bid) & 255) == 0))
            s_copy[tid] = s_state4[tid];
    }

    // ---- tail: s in [4087,4095] have incomplete in-loop coverage.
    // Blocks 247..254 recompute all 64 outputs for s = bid+3840 from their
    // parked copy (idempotent). Block 255 stages row 4095 first (never staged
    // in-loop), then computes outputs[4095].
    if (bid >= 247) {
        const int s = bid + 3840;   // 4087..4095
        if (bid == 255) {
            const unsigned* p =
                (const unsigned*)(out_states + (size_t)4095 * H + scol);
            uint4 v = cpoll1(p);
            while ((v.x == SENT) | (v.y == SENT) | (v.z == SENT) | (v.w == SENT)) {
                __builtin_amdgcn_s_sleep(2);
                v = cpoll1(p);
            }
            float4 f;
            f.x = __uint_as_float(v.x); f.y = __uint_as_float(v.y);
            f.z = __uint_as_float(v.z); f.w = __uint_as_float(v.w);
            s_copy[sslot] = f;
        }
        __syncthreads();   // parked/staged copy visible cross-wave
#pragma unroll
        for (int i = 0; i < 4; ++i)
            out_dot(s, wave * 4 + i);
    }
}

extern "C" void kernel_launch(void* const* d_in, const int* in_sizes, int n_in,
                              void* d_out, int out_size, void* d_ws, size_t ws_size,
                              hipStream_t stream) {
    const float* inputs = (const float*)d_in[0];
    const float* W_in   = (const float*)d_in[1];
    const float* W_res  = (const float*)d_in[2];
    const float* W_out  = (const float*)d_in[3];

    float* outputs = (float*)d_out;                        // (SEQ, OUTD)
    float* states  = (float*)d_out + (size_t)SEQ * OUTD;   // (SEQ, H)

    // Sentinel-prefill states: one-hop data-poll handshake ground truth.
    (void)hipMemsetAsync(states, 0x7F, (size_t)SEQ * H * sizeof(float), stream);

    void* args[] = { (void*)&inputs, (void*)&W_in, (void*)&W_res,
                     (void*)&W_out, (void*)&states, (void*)&outputs };
    (void)hipLaunchCooperativeKernel((void*)esn_scan, dim3(NBLK), dim3(NTHR),
                                     args, 0, stream);
}

// Round 15
// 8397.089 us; speedup vs baseline: 1.6856x; 1.6856x over previous
//
#include <hip/hip_runtime.h>

#define H 4096
#define IN 64
#define OUTD 64
#define SEQ 4096
#define NBLK 256
#define ROWS_PER_BLK 16
#define NTHR 1024
#define SENT 0x7F7F7F7Fu   // 3.39e38f; tanh output in [-1,1] can never equal it

// ---- device-coherent (L2-bypassing, MALL-point) accessors -----------------
__device__ __forceinline__ uint4 cpoll1(const unsigned* p) {
    uint4 v;
    asm volatile("global_load_dwordx4 %0, %1, off sc0 sc1\n\t"
                 "s_waitcnt vmcnt(0)"
                 : "=&v"(v) : "v"(p) : "memory");
    return v;
}
__device__ __forceinline__ void coherent_store_f32(float* p, float v) {
    asm volatile("global_store_dword %0, %1, off sc0 sc1"
                 :: "v"(p), "v"(v) : "memory");
}

__device__ __forceinline__ float row16_allreduce(float x) {
    x += __int_as_float(__builtin_amdgcn_update_dpp(0, __float_as_int(x), 0x128, 0xf, 0xf, false)); // row_ror:8
    x += __int_as_float(__builtin_amdgcn_update_dpp(0, __float_as_int(x), 0x124, 0xf, 0xf, false)); // row_ror:4
    x += __int_as_float(__builtin_amdgcn_update_dpp(0, __float_as_int(x), 0x122, 0xf, 0xf, false)); // row_ror:2
    x += __int_as_float(__builtin_amdgcn_update_dpp(0, __float_as_int(x), 0x121, 0xf, 0xf, false)); // row_ror:1
    return x;
}
__device__ __forceinline__ float quad4_allreduce(float x) {
    x += __int_as_float(__builtin_amdgcn_update_dpp(0, __float_as_int(x), 0xB1, 0xf, 0xf, false)); // perm 1,0,3,2
    x += __int_as_float(__builtin_amdgcn_update_dpp(0, __float_as_int(x), 0x4E, 0xf, 0xf, false)); // perm 2,3,0,1
    return x;
}

__global__ __launch_bounds__(NTHR, 4)
void esn_scan(const float* __restrict__ inputs,   // (SEQ, IN)
              const float* __restrict__ W_in,     // (H, IN)
              const float* __restrict__ W_res,    // (H, H)
              float* __restrict__ out_states)     // (SEQ, H), sentinel-prefilled
{
    __shared__ alignas(16) float4 s_state4[H / 4];        // 1024 swizzled quads
    __shared__ alignas(16) float s_win[ROWS_PER_BLK][65]; // padded
    __shared__ alignas(16) float s_part[2][16][20];       // [parity][k(wave)][row+pad]
    __shared__ alignas(16) float s_u[IN];                 // wave0-local

    const int tid  = threadIdx.x;
    const int row0 = blockIdx.x * ROWS_PER_BLK;
    const int wave = tid >> 6;
    const int lane = tid & 63;
    const int rg   = lane >> 4;   // 0..3
    const int cgi  = lane & 15;   // 0..15
    const int col0 = wave * 256 + cgi * 16;

    // staging: thread polls ONE 16B quad: producer sp = tid>>2, sub-quad sq = tid&3
    // LDS slot = 64*(sp>>4) + 16*sq + (sp&15)  == wave-local region [64w, 64w+64)
    const int sp    = tid >> 2;
    const int sq    = tid & 3;
    const int sslot = 64 * (sp >> 4) + 16 * sq + (sp & 15);
    const int scol  = sp * 16 + sq * 4;

    for (int idx = tid; idx < ROWS_PER_BLK * IN; idx += NTHR)
        s_win[idx >> 6][idx & 63] = W_in[(size_t)row0 * IN + idx];

    float w[4][16];
#pragma unroll
    for (int j = 0; j < 4; ++j) {
        const float* src = W_res + (size_t)(row0 + 4 * rg + j) * H + col0;
#pragma unroll
        for (int q = 0; q < 4; ++q) {
            float4 v = *(const float4*)(src + 4 * q);
            w[j][4 * q + 0] = v.x; w[j][4 * q + 1] = v.y;
            w[j][4 * q + 2] = v.z; w[j][4 * q + 3] = v.w;
        }
    }
    __syncthreads();   // s_win visible to wave0 before first phase-3

    for (int t = 0; t < SEQ; ++t) {
        const int par = t & 1;
        // ---- stage u_t (wave0-local; program-order safe vs phase-3 reads)
        if (tid < 16)
            ((float4*)s_u)[tid] = ((const float4*)(inputs + (size_t)t * IN))[tid];
        // ---- stage state row t-1: one-hop 16B poll with calibrated backoff.
        // NO B1: staging/readback strictly wave-local; each wave starts FMA as
        // soon as ITS producers land. Backoff throttles poll traffic so freed
        // waves don't saturate the fabric (R6 failure mode).
        if (t == 0) {
            s_state4[sslot] = make_float4(0.f, 0.f, 0.f, 0.f);
        } else {
            const unsigned* p =
                (const unsigned*)(out_states + (size_t)(t - 1) * H + scol);
            uint4 v = cpoll1(p);
            if ((v.x == SENT) | (v.y == SENT) | (v.z == SENT) | (v.w == SENT)) {
                __builtin_amdgcn_s_sleep(8);   // skip publish dead-window
                for (;;) {
                    v = cpoll1(p);
                    if ((v.x != SENT) & (v.y != SENT) &
                        (v.z != SENT) & (v.w != SENT))
                        break;
                    __builtin_amdgcn_s_sleep(2);
                }
            }
            float4 f;
            f.x = __uint_as_float(v.x); f.y = __uint_as_float(v.y);
            f.z = __uint_as_float(v.z); f.w = __uint_as_float(v.w);
            s_state4[sslot] = f;
        }

        // ---- phase 2: 4 rows x 16 cols of FMA per lane, weights in VGPRs
        float a0 = 0.f, a1 = 0.f, a2 = 0.f, a3 = 0.f;
#pragma unroll
        for (int q = 0; q < 4; ++q) {
            float4 sv = s_state4[wave * 64 + q * 16 + cgi];
            a0 = fmaf(w[0][4*q+0], sv.x, a0); a0 = fmaf(w[0][4*q+1], sv.y, a0);
            a0 = fmaf(w[0][4*q+2], sv.z, a0); a0 = fmaf(w[0][4*q+3], sv.w, a0);
            a1 = fmaf(w[1][4*q+0], sv.x, a1); a1 = fmaf(w[1][4*q+1], sv.y, a1);
            a1 = fmaf(w[1][4*q+2], sv.z, a1); a1 = fmaf(w[1][4*q+3], sv.w, a1);
            a2 = fmaf(w[2][4*q+0], sv.x, a2); a2 = fmaf(w[2][4*q+1], sv.y, a2);
            a2 = fmaf(w[2][4*q+2], sv.z, a2); a2 = fmaf(w[2][4*q+3], sv.w, a2);
            a3 = fmaf(w[3][4*q+0], sv.x, a3); a3 = fmaf(w[3][4*q+1], sv.y, a3);
            a3 = fmaf(w[3][4*q+2], sv.z, a3); a3 = fmaf(w[3][4*q+3], sv.w, a3);
        }
        a0 = row16_allreduce(a0);
        a1 = row16_allreduce(a1);
        a2 = row16_allreduce(a2);
        a3 = row16_allreduce(a3);
        if (cgi == 0) {
            float4 pv; pv.x = a0; pv.y = a1; pv.z = a2; pv.w = a3;
            *(float4*)&s_part[par][wave][4 * rg] = pv;
        }
        __syncthreads();   // B2: the only barrier per step

        // ---- phase 3: wave0 alone finishes all 16 rows; ONE coalesced 64B
        // publish. Waves 1..15 fall straight through to next step's polls.
        if (wave == 0) {
            const int row = lane >> 2;  // 0..15
            const int j   = lane & 3;   // partial group
            float v = s_part[par][4*j+0][row] + s_part[par][4*j+1][row]
                    + s_part[par][4*j+2][row] + s_part[par][4*j+3][row];
#pragma unroll
            for (int e = 0; e < 16; ++e)
                v = fmaf(s_win[row][16*j + e], s_u[16*j + e], v);
            v = quad4_allreduce(v);
            if (j == 0)
                coherent_store_f32(&out_states[(size_t)t * H + row0 + row],
                                   tanhf(v));
        }
        // s_part reuse protected by parity + B2 ordering.
    }
}

__device__ __forceinline__ float wave64_allreduce(float x) {
#pragma unroll
    for (int m = 1; m < 64; m <<= 1) x += __shfl_xor(x, m, 64);
    return x;
}

// One wave per timestep s; states row cached in 16 float4 regs across all 64 o.
__global__ __launch_bounds__(NTHR)
void esn_out(const float* __restrict__ inputs,
             const float* __restrict__ W_out,    // (OUTD, 4161) row-major
             const float* __restrict__ states,   // (SEQ, H)
             float* __restrict__ outputs)        // (SEQ, OUTD)
{
    const int wv   = threadIdx.x >> 6;
    const int lane = threadIdx.x & 63;
    const int s    = blockIdx.x * 16 + wv;
    const int K    = 1 + IN + H; // 4161

    const float4* st4 = (const float4*)(states + (size_t)s * H);
    float4 sq[16];
#pragma unroll
    for (int k = 0; k < 16; ++k)
        sq[k] = st4[64 * k + lane];
    float4 iq = make_float4(0.f, 0.f, 0.f, 0.f);
    if (lane < 16)
        iq = ((const float4*)(inputs + (size_t)s * IN))[lane];

    for (int o = 0; o < OUTD; ++o) {
        const float* wrow = W_out + (size_t)o * K;
        float acc = 0.f;
#pragma unroll
        for (int k = 0; k < 16; ++k) {
            float4 wq;   // wrow+65 is only 4B-aligned -> memcpy (dword loads)
            __builtin_memcpy(&wq, wrow + 65 + 4 * (64 * k + lane), 16);
            acc = fmaf(wq.x, sq[k].x, acc);
            acc = fmaf(wq.y, sq[k].y, acc);
            acc = fmaf(wq.z, sq[k].z, acc);
            acc = fmaf(wq.w, sq[k].w, acc);
        }
        if (lane < 16) {
            float4 wi;
            __builtin_memcpy(&wi, wrow + 1 + 4 * lane, 16);
            acc = fmaf(wi.x, iq.x, acc);
            acc = fmaf(wi.y, iq.y, acc);
            acc = fmaf(wi.z, iq.z, acc);
            acc = fmaf(wi.w, iq.w, acc);
            if (lane == 0) acc += wrow[0];   // bias
        }
        acc = wave64_allreduce(acc);
        if (lane == 0) outputs[(size_t)s * OUTD + o] = acc;
    }
}

extern "C" void kernel_launch(void* const* d_in, const int* in_sizes, int n_in,
                              void* d_out, int out_size, void* d_ws, size_t ws_size,
                              hipStream_t stream) {
    const float* inputs = (const float*)d_in[0];
    const float* W_in   = (const float*)d_in[1];
    const float* W_res  = (const float*)d_in[2];
    const float* W_out  = (const float*)d_in[3];

    float* outputs = (float*)d_out;                        // (SEQ, OUTD)
    float* states  = (float*)d_out + (size_t)SEQ * OUTD;   // (SEQ, H)

    // Sentinel-prefill states: one-hop data-poll handshake ground truth.
    (void)hipMemsetAsync(states, 0x7F, (size_t)SEQ * H * sizeof(float), stream);

    void* args[] = { (void*)&inputs, (void*)&W_in, (void*)&W_res, (void*)&states };
    (void)hipLaunchCooperativeKernel((void*)esn_scan, dim3(NBLK), dim3(NTHR),
                                     args, 0, stream);

    esn_out<<<dim3(SEQ / 16), dim3(NTHR), 0, stream>>>(inputs, W_out, states, outputs);
}